// Round 21
// baseline (277.401 us; speedup 1.0000x reference)
//
#include <hip/hip_runtime.h>
#include <math.h>

#define HID   1024
#define STT   4096
#define MTOK  4096   // B*L
#define LSEQ  2048
#define NCHUNK 64
#define CHUNK  32
#define VOCAB  62

typedef __attribute__((ext_vector_type(8))) short short8v;
typedef __attribute__((ext_vector_type(4))) float float4v;

typedef const __attribute__((address_space(1))) void* gptr_t;
typedef __attribute__((address_space(3))) void* lptr_t;

__device__ __forceinline__ float sigmoidf_(float x) {
    return 1.0f / (1.0f + __expf(-x));
}
__device__ __forceinline__ unsigned short f2bf(float f) {
    unsigned int u = __float_as_uint(f);
    unsigned int r = (u + 0x7fffu + ((u >> 16) & 1u)) >> 16;
    return (unsigned short)r;
}
__device__ __forceinline__ float bf2f(unsigned short b) {
    return __uint_as_float(((unsigned int)b) << 16);
}

// ---------------- fused prologue (block-range partitioned) ----------------
__global__ __launch_bounds__(256) void fused_pre(
    const int* __restrict__ tokens, const float* __restrict__ embed_w,
    const float* __restrict__ norm_w, const float* __restrict__ in_w,
    const float* __restrict__ out_w, const float* __restrict__ head_w,
    const float* __restrict__ out_b, const float* __restrict__ head_b,
    unsigned short* __restrict__ in_wT, unsigned short* __restrict__ xn,
    unsigned short* __restrict__ W2T, float* __restrict__ E_head)
{
    __shared__ float sh[1056];
    int bid = blockIdx.x;
    int tid = threadIdx.x;
    if (bid < 16384) {
        float (*tile)[33] = (float (*)[33])sh;
        int c0 = (bid & 511) * 32, r0 = (bid >> 9) * 32;
        int r = tid >> 3, c4 = (tid & 7) << 2;
        float4 v = *(const float4*)(in_w + (size_t)(r0 + r) * 16384 + c0 + c4);
        tile[r][c4 + 0] = v.x; tile[r][c4 + 1] = v.y;
        tile[r][c4 + 2] = v.z; tile[r][c4 + 3] = v.w;
        __syncthreads();
        int oc = tid >> 3;
        int orr = (tid & 7) << 2;
        ushort4 o;
        o.x = f2bf(tile[orr + 0][oc]); o.y = f2bf(tile[orr + 1][oc]);
        o.z = f2bf(tile[orr + 2][oc]); o.w = f2bf(tile[orr + 3][oc]);
        *(ushort4*)(in_wT + (size_t)(c0 + oc) * 1024 + r0 + orr) = o;
    } else if (bid < 20480) {
        int m = bid - 16384;
        int tok = tokens[m];
        float4 x = ((const float4*)(embed_w + (size_t)tok * HID))[tid];
        float ss = x.x * x.x + x.y * x.y + x.z * x.z + x.w * x.w;
        for (int off = 32; off > 0; off >>= 1) ss += __shfl_down(ss, off);
        if ((tid & 63) == 0) sh[tid >> 6] = ss;
        __syncthreads();
        float tot = sh[0] + sh[1] + sh[2] + sh[3];
        float scale = rsqrtf(tot / (float)HID + 1e-6f);
        float4 w4 = ((const float4*)norm_w)[tid];
        ushort4 o;
        o.x = f2bf(x.x * scale * w4.x); o.y = f2bf(x.y * scale * w4.y);
        o.z = f2bf(x.z * scale * w4.z); o.w = f2bf(x.w * scale * w4.w);
        *(ushort4*)(xn + (size_t)m * HID + (tid << 2)) = o;
    } else if (bid < 21504) {
        float (*red)[4][64] = (float (*)[4][64])sh;
        int jc = tid >> 6, n = tid & 63;
        bool act = n < VOCAB;
        int k0 = (bid - 20480) * 4;
        float a[4] = {0.f, 0.f, 0.f, 0.f};
        int j0 = jc * 256;
        const float* w0 = out_w + (size_t)(k0 + 0) * HID;
        const float* w1 = out_w + (size_t)(k0 + 1) * HID;
        const float* w2 = out_w + (size_t)(k0 + 2) * HID;
        const float* w3 = out_w + (size_t)(k0 + 3) * HID;
        #pragma unroll 4
        for (int j = j0; j < j0 + 256; j++) {
            float h = act ? head_w[(size_t)j * VOCAB + n] : 0.f;
            a[0] = fmaf(w0[j], h, a[0]);
            a[1] = fmaf(w1[j], h, a[1]);
            a[2] = fmaf(w2[j], h, a[2]);
            a[3] = fmaf(w3[j], h, a[3]);
        }
        #pragma unroll
        for (int i = 0; i < 4; i++) red[jc][i][n] = a[i];
        __syncthreads();
        if (jc == 0) {
            #pragma unroll
            for (int i = 0; i < 4; i++) {
                float s = red[0][i][n] + red[1][i][n] + red[2][i][n] + red[3][i][n];
                W2T[(size_t)n * STT + k0 + i] = f2bf(s);
            }
        }
    } else {
        float (*red)[4][64] = (float (*)[4][64])sh;
        int jc = tid >> 6, n = tid & 63;
        bool act = n < VOCAB;
        int t = bid - 21504;
        const float* src = (t < VOCAB) ? (embed_w + (size_t)t * HID) : out_b;
        float acc = 0.f;
        if (act) {
            int j0 = jc * 256;
            #pragma unroll 4
            for (int j = j0; j < j0 + 256; j++)
                acc = fmaf(src[j], head_w[(size_t)j * VOCAB + n], acc);
        }
        red[jc][0][n] = acc;
        __syncthreads();
        if (tid < 64) {
            float s = red[0][0][n] + red[1][0][n] + red[2][0][n] + red[3][0][n];
            if (t == VOCAB && act) s += head_b[n];
            E_head[t * 64 + n] = s;
        }
    }
}

// ---------------- MFMA GEMM 1 + fused gates + fused chunk-scan (frozen) ------
__global__ __launch_bounds__(512, 2) void gemm_in_mfma(
    const unsigned short* __restrict__ A, const unsigned short* __restrict__ B,
    const float* __restrict__ bias,
    unsigned short* __restrict__ a_out, unsigned short* __restrict__ bx_out,
    unsigned short* __restrict__ c_out,
    float* __restrict__ chunkA, float* __restrict__ chunkH)
{
    extern __shared__ unsigned short lds[];   // 2 bufs * 32768 shorts = 128 KiB
    int tid = threadIdx.x;
    int wid = tid >> 6, lane = tid & 63;
    int wg = blockIdx.x;
    int xcd = wg & 7, loc = wg >> 3;
    int by = ((xcd >> 1) << 2) + (loc & 3);
    int bx = ((xcd & 1) << 5) + (loc >> 2);
    int m0 = by * 256, s0 = bx * 64;
    int wm = wid >> 2, wn = wid & 3;
    int lr = lane & 15, lk = lane >> 4;

    int cb0 = wid * 64, cb1 = 512 + wid * 64;
    int p0 = cb0 + lane, p1 = cb1 + lane;
    int row0 = p0 >> 2, ks0 = (p0 & 3) ^ ((row0 >> 1) & 3);
    int row1 = p1 >> 2, ks1 = (p1 & 3) ^ ((row1 >> 1) & 3);
    int arow0 = m0 + row0, arow1 = m0 + row1;
    int brow0 = ((row0 >> 6) << 12) + s0 + (row0 & 63);
    int brow1 = ((row1 >> 6) << 12) + s0 + (row1 & 63);

#define SHALF(grow0, grow1, b, which, kt, kk) do {                               \
    unsigned short* _d = lds + (b) * 32768 + (which) * 16384 + (kk) * 8192;      \
    __builtin_amdgcn_global_load_lds(                                            \
        (gptr_t)(const void*)(((which) ? B : A) + (size_t)(grow0) * 1024 +       \
                              (kt) * 64 + (kk) * 32 + ks0 * 8),                  \
        (lptr_t)(void*)(_d + (size_t)cb0 * 8), 16, 0, 0);                        \
    __builtin_amdgcn_global_load_lds(                                            \
        (gptr_t)(const void*)(((which) ? B : A) + (size_t)(grow1) * 1024 +       \
                              (kt) * 64 + (kk) * 32 + ks1 * 8),                  \
        (lptr_t)(void*)(_d + (size_t)cb1 * 8), 16, 0, 0);                        \
} while (0)

    int ksw = lk ^ ((lr >> 1) & 3);

#define RD_A(b, kk, mf) \
    (*(const short8v*)&lds[(b) * 32768 + (kk) * 8192 + \
        (((wm * 128 + (mf) * 16 + lr) << 2) + ksw) * 8])
#define RD_B(b, kk, nf) \
    (*(const short8v*)&lds[(b) * 32768 + 16384 + (kk) * 8192 + \
        ((((nf) * 64 + wn * 16 + lr) << 2) + ksw) * 8])

#define MFMA8x2(AF, B0, B1, n0i, n1i) do {                                       \
    __builtin_amdgcn_s_setprio(1);                                               \
    _Pragma("unroll")                                                            \
    for (int mf = 0; mf < 8; mf++) {                                             \
        acc[mf][n0i] = __builtin_amdgcn_mfma_f32_16x16x32_bf16(                  \
            (AF)[mf], (B0), acc[mf][n0i], 0, 0, 0);                              \
        acc[mf][n1i] = __builtin_amdgcn_mfma_f32_16x16x32_bf16(                  \
            (AF)[mf], (B1), acc[mf][n1i], 0, 0, 0);                              \
    }                                                                            \
    __builtin_amdgcn_s_setprio(0);                                               \
} while (0)

#define BAR_IN()  do { __builtin_amdgcn_s_barrier();                              \
    asm volatile("s_waitcnt lgkmcnt(0)" ::: "memory");                           \
    __builtin_amdgcn_sched_barrier(0); } while (0)
#define BAR_OUT() do { asm volatile("" ::: "memory");                             \
    __builtin_amdgcn_s_barrier(); } while (0)

    float4v acc[8][4];
    float4v z = {0.f, 0.f, 0.f, 0.f};
    #pragma unroll
    for (int i = 0; i < 8; i++)
        #pragma unroll
        for (int j = 0; j < 4; j++) acc[i][j] = z;

    SHALF(arow0, arow1, 0, 0, 0, 0); SHALF(brow0, brow1, 0, 1, 0, 0);
    SHALF(arow0, arow1, 0, 0, 0, 1); SHALF(brow0, brow1, 0, 1, 0, 1);
    asm volatile("s_waitcnt vmcnt(0)" ::: "memory");
    __builtin_amdgcn_s_barrier();

    short8v af[8], bf0, bf1;

    for (int kt = 0; kt < 16; ++kt) {
        int cur = kt & 1, nxt = cur ^ 1;
        int ktn = kt < 15 ? kt + 1 : 15;
        #pragma unroll
        for (int mf = 0; mf < 8; mf++) af[mf] = RD_A(cur, 0, mf);
        bf0 = RD_B(cur, 0, 0); bf1 = RD_B(cur, 0, 1);
        asm volatile("s_waitcnt vmcnt(4)" ::: "memory");
        SHALF(arow0, arow1, nxt, 0, ktn, 0);
        BAR_IN();
        MFMA8x2(af, bf0, bf1, 0, 1);
        BAR_OUT();
        bf0 = RD_B(cur, 0, 2); bf1 = RD_B(cur, 0, 3);
        SHALF(brow0, brow1, nxt, 1, ktn, 0);
        BAR_IN();
        MFMA8x2(af, bf0, bf1, 2, 3);
        BAR_OUT();
        #pragma unroll
        for (int mf = 0; mf < 8; mf++) af[mf] = RD_A(cur, 1, mf);
        bf0 = RD_B(cur, 1, 0); bf1 = RD_B(cur, 1, 1);
        asm volatile("s_waitcnt vmcnt(4)" ::: "memory");
        SHALF(arow0, arow1, nxt, 0, ktn, 1);
        BAR_IN();
        MFMA8x2(af, bf0, bf1, 0, 1);
        BAR_OUT();
        bf0 = RD_B(cur, 1, 2); bf1 = RD_B(cur, 1, 3);
        SHALF(brow0, brow1, nxt, 1, ktn, 1);
        BAR_IN();
        MFMA8x2(af, bf0, bf1, 2, 3);
        BAR_OUT();
    }

    int s = s0 + wn * 16 + lr;
    float b_xg = bias[s];
    float b_a  = bias[4096 + s];
    float b_b  = bias[8192 + s];
    float b_c  = bias[12288 + s];
    int rbase = lk << 2;
    int bb = m0 >> 11;
    int t0 = m0 & 2047;
    int ch = bb * STT + s;

    #pragma unroll
    for (int cc = 0; cc < 4; cc++) {
        float Afr[2], Hfr[2];
        #pragma unroll
        for (int e = 0; e < 2; e++) {
            int mf = cc * 2 + e;
            float Al = 1.f, Hl = 0.f;
            #pragma unroll
            for (int q = 0; q < 4; q++) {
                int m = m0 + wm * 128 + mf * 16 + rbase + q;
                size_t idx = (size_t)m * STT + s;
                float xg = acc[mf][0][q] + b_xg;
                float av = sigmoidf_(acc[mf][1][q] + b_a);
                float bxv = sigmoidf_(acc[mf][2][q] + b_b) * xg;
                float cv = sigmoidf_(acc[mf][3][q] + b_c);
                unsigned short au = f2bf(av), bu = f2bf(bxv);
                a_out[idx]  = au;
                bx_out[idx] = bu;
                c_out[idx]  = f2bf(cv);
                float ar = bf2f(au), br = bf2f(bu);
                Hl = fmaf(ar, Hl, br);
                Al = ar * Al;
            }
            #pragma unroll
            for (int d = 1; d <= 2; d <<= 1) {
                float Ap = __shfl(Al, lane - (d << 4));
                float Hp = __shfl(Hl, lane - (d << 4));
                if (lk >= d) { Hl = fmaf(Al, Hp, Hl); Al = Al * Ap; }
            }
            Afr[e] = Al; Hfr[e] = Hl;
        }
        if (lk == 3) {
            float Ac = Afr[1] * Afr[0];
            float Hc = fmaf(Afr[1], Hfr[0], Hfr[1]);
            int qg = (t0 >> 5) + wm * 4 + cc;
            chunkA[ch * NCHUNK + qg] = Ac;
            chunkH[ch * NCHUNK + qg] = Hc;
        }
    }
#undef SHALF
#undef RD_A
#undef RD_B
#undef MFMA8x2
#undef BAR_IN
#undef BAR_OUT
}

// ---------------- scan2 + logits init (block-range partitioned) -------------
// blocks 0..31    : per-channel serial scan over 64 chunk affines -> carry
// blocks 32..1055 : logits[m][n] = E_head[tok[m]][n] + bias2[n]  (4 tokens/blk)
__global__ __launch_bounds__(256) void scan2_init(
    const float* __restrict__ chunkA, const float* __restrict__ chunkH,
    const float* __restrict__ E_head, const int* __restrict__ tokens,
    float* __restrict__ carry, float* __restrict__ logits)
{
    int bid = blockIdx.x;
    int tid = threadIdx.x;
    if (bid < 32) {
        int ch = bid * 256 + tid;
        float c = 0.f;
        for (int q = 0; q < NCHUNK; q++) {
            carry[ch * NCHUNK + q] = c;
            c = fmaf(chunkA[ch * NCHUNK + q], c, chunkH[ch * NCHUNK + q]);
        }
    } else {
        int m = (bid - 32) * 4 + (tid >> 6);
        int n = tid & 63;
        if (n < VOCAB) {
            int tok = tokens[m];
            logits[(size_t)m * VOCAB + n] =
                E_head[tok * 64 + n] + E_head[VOCAB * 64 + n];
        }
    }
}

// ---------------- fused scan3 + logits GEMM (atomic accumulate) -------------
// grid 512: mt = wg&31 (128-token tile), sl = wg>>5 (16 slices x 256 channels).
// Per 128-ch subtile ks (2): wave w scans chunk w (carry-init, 2 ch/thread),
// writes bf16 y into LDS [128][128] XOR-chunk swizzle; stages W2T subtile;
// 32 MFMA accumulate. Epilogue atomicAdds into logits (init'd by scan2_init).
__global__ __launch_bounds__(256) void scan_logits(
    const unsigned short* __restrict__ a_buf, const unsigned short* __restrict__ bx_buf,
    const unsigned short* __restrict__ c_buf, const float* __restrict__ carry,
    const unsigned short* __restrict__ W2T, float* __restrict__ logits)
{
    __shared__ __align__(16) unsigned short y_lds[128 * 128];   // 32 KiB
    __shared__ __align__(16) unsigned short b_lds[64 * 128];    // 16 KiB
    int tid = threadIdx.x;
    int wg = blockIdx.x;
    int mt = wg & 31, sl = wg >> 5;
    int m0 = mt * 128;
    int bb = m0 >> 11;
    int q0 = (m0 & 2047) >> 5;
    int lane = tid & 63, wid = tid >> 6;
    int lr = lane & 15, lk = lane >> 4;

    float4v acc[2][4];
    float4v z = {0.f, 0.f, 0.f, 0.f};
    #pragma unroll
    for (int e = 0; e < 2; e++)
        #pragma unroll
        for (int nf = 0; nf < 4; nf++) acc[e][nf] = z;

    for (int ks = 0; ks < 2; ++ks) {
        int sbase = sl * 256 + ks * 128;
        #pragma unroll
        for (int i = 0; i < 4; i++) {
            int cb = i * 256 + wid * 64;
            int p = cb + lane;
            int row = p >> 4, csw = p & 15;
            int c = csw ^ (row & 7);
            __builtin_amdgcn_global_load_lds(
                (gptr_t)(const void*)(W2T + (size_t)row * STT + sbase + c * 8),
                (lptr_t)(void*)(b_lds + (size_t)cb * 8), 16, 0, 0);
        }
        {
            int chq = wid;
            int s = sbase + lane * 2;
            int q = q0 + chq;
            size_t cidx = ((size_t)(bb * STT + s)) * NCHUNK + q;
            float h0 = carry[cidx];
            float h1 = carry[cidx + NCHUNK];
            size_t gb = (size_t)(m0 + chq * 32) * STT + s;
            const unsigned int* ap = (const unsigned int*)(a_buf + gb);
            const unsigned int* bp = (const unsigned int*)(bx_buf + gb);
            const unsigned int* cp = (const unsigned int*)(c_buf + gb);
            const int stride = STT / 2;
            #pragma unroll 4
            for (int i = 0; i < 32; i++) {
                unsigned int au = ap[(size_t)i * stride];
                unsigned int bu = bp[(size_t)i * stride];
                unsigned int cu = cp[(size_t)i * stride];
                float a0 = bf2f((unsigned short)(au & 0xffff));
                float a1 = bf2f((unsigned short)(au >> 16));
                float b0 = bf2f((unsigned short)(bu & 0xffff));
                float b1 = bf2f((unsigned short)(bu >> 16));
                float c0 = bf2f((unsigned short)(cu & 0xffff));
                float c1 = bf2f((unsigned short)(cu >> 16));
                h0 = fmaf(a0, h0, b0);
                h1 = fmaf(a1, h1, b1);
                unsigned int yp = (unsigned int)f2bf(c0 * h0) |
                                  ((unsigned int)f2bf(c1 * h1) << 16);
                int row = chq * 32 + i;
                int cw = (lane >> 2) ^ (row & 7);
                *(unsigned int*)&y_lds[row * 128 + (cw << 3) + (lane & 3) * 2] = yp;
            }
        }
        __syncthreads();
        #pragma unroll
        for (int kt2 = 0; kt2 < 4; kt2++) {
            short8v af[2], bf[4];
            #pragma unroll
            for (int e = 0; e < 2; e++) {
                int row = (wid * 2 + e) * 16 + lr;
                int c = kt2 * 4 + lk;
                af[e] = *(const short8v*)&y_lds[row * 128 + ((c ^ (row & 7)) << 3)];
            }
            #pragma unroll
            for (int nf = 0; nf < 4; nf++) {
                int row = nf * 16 + lr;
                int c = kt2 * 4 + lk;
                bf[nf] = *(const short8v*)&b_lds[row * 128 + ((c ^ (row & 7)) << 3)];
            }
            __builtin_amdgcn_s_setprio(1);
            #pragma unroll
            for (int e = 0; e < 2; e++)
                #pragma unroll
                for (int nf = 0; nf < 4; nf++)
                    acc[e][nf] = __builtin_amdgcn_mfma_f32_16x16x32_bf16(
                        af[e], bf[nf], acc[e][nf], 0, 0, 0);
            __builtin_amdgcn_s_setprio(0);
        }
        __syncthreads();
    }

    int rbase = lk << 2;
    #pragma unroll
    for (int e = 0; e < 2; e++)
        #pragma unroll
        for (int nf = 0; nf < 4; nf++) {
            int n = nf * 16 + lr;
            if (n < VOCAB) {
                #pragma unroll
                for (int q = 0; q < 4; q++) {
                    int m = m0 + (wid * 2 + e) * 16 + rbase + q;
                    atomicAdd(&logits[(size_t)m * VOCAB + n], acc[e][nf][q]);
                }
            }
        }
}

extern "C" void kernel_launch(void* const* d_in, const int* in_sizes, int n_in,
                              void* d_out, int out_size, void* d_ws, size_t ws_size,
                              hipStream_t stream) {
    const int*   tokens  = (const int*)d_in[0];
    const float* embed_w = (const float*)d_in[1];
    const float* norm_w  = (const float*)d_in[2];
    const float* in_w    = (const float*)d_in[3];
    const float* in_b    = (const float*)d_in[4];
    const float* out_w   = (const float*)d_in[5];
    const float* out_b   = (const float*)d_in[6];
    const float* head_w  = (const float*)d_in[7];
    const float* head_b  = (const float*)d_in[8];
    float* logits = (float*)d_out;

    char* w = (char*)d_ws;
    unsigned short* a_buf  = (unsigned short*)w;                    // 32 MiB
    unsigned short* bx_buf = (unsigned short*)(w + 33554432);       // 32 MiB
    unsigned short* c_buf  = (unsigned short*)(w + 67108864);       // 32 MiB
    unsigned short* W2T    = (unsigned short*)(w + 100663296);      // 512 KiB
    float*          E_head = (float*)(w + 101711872);               // 16 KiB
    unsigned short* in_wT  = (unsigned short*)(w + 167772160);      // 32 MiB
    unsigned short* xn     = (unsigned short*)(w + 201326592);      // 8 MiB
    float* chunkA = (float*)(w + 209715200);
    float* chunkH = chunkA + 8192 * NCHUNK;
    float* carry  = chunkH + 8192 * NCHUNK;

    hipLaunchKernelGGL(fused_pre, dim3(16384 + 4096 + 1024 + VOCAB + 1), dim3(256), 0, stream,
                       tokens, embed_w, norm_w, in_w, out_w, head_w, out_b, head_b,
                       in_wT, xn, W2T, E_head);
    hipLaunchKernelGGL(gemm_in_mfma, dim3(1024), dim3(512), 131072, stream,
                       xn, in_wT, in_b, a_buf, bx_buf, c_buf, chunkA, chunkH);
    hipLaunchKernelGGL(scan2_init, dim3(32 + 1024), dim3(256), 0, stream,
                       chunkA, chunkH, E_head, tokens, carry, logits);
    hipLaunchKernelGGL(scan_logits, dim3(512), dim3(256), 0, stream,
                       a_buf, bx_buf, c_buf, carry, W2T, logits);
}

// Round 22
// 264.297 us; speedup vs baseline: 1.0496x; 1.0496x over previous
//
#include <hip/hip_runtime.h>
#include <math.h>

#define HID   1024
#define STT   4096
#define MTOK  4096   // B*L
#define LSEQ  2048
#define NCHUNK 64
#define CHUNK  32
#define VOCAB  62

typedef __attribute__((ext_vector_type(8))) short short8v;
typedef __attribute__((ext_vector_type(4))) float float4v;

typedef const __attribute__((address_space(1))) void* gptr_t;
typedef __attribute__((address_space(3))) void* lptr_t;

__device__ __forceinline__ float sigmoidf_(float x) {
    return 1.0f / (1.0f + __expf(-x));
}
__device__ __forceinline__ unsigned short f2bf(float f) {
    unsigned int u = __float_as_uint(f);
    unsigned int r = (u + 0x7fffu + ((u >> 16) & 1u)) >> 16;
    return (unsigned short)r;
}
__device__ __forceinline__ float bf2f(unsigned short b) {
    return __uint_as_float(((unsigned int)b) << 16);
}

// ---------------- fused prologue (block-range partitioned) ----------------
__global__ __launch_bounds__(256) void fused_pre(
    const int* __restrict__ tokens, const float* __restrict__ embed_w,
    const float* __restrict__ norm_w, const float* __restrict__ in_w,
    const float* __restrict__ out_w, const float* __restrict__ head_w,
    const float* __restrict__ out_b, const float* __restrict__ head_b,
    unsigned short* __restrict__ in_wT, unsigned short* __restrict__ xn,
    unsigned short* __restrict__ W2T, float* __restrict__ E_head)
{
    __shared__ float sh[1056];
    int bid = blockIdx.x;
    int tid = threadIdx.x;
    if (bid < 16384) {
        float (*tile)[33] = (float (*)[33])sh;
        int c0 = (bid & 511) * 32, r0 = (bid >> 9) * 32;
        int r = tid >> 3, c4 = (tid & 7) << 2;
        float4 v = *(const float4*)(in_w + (size_t)(r0 + r) * 16384 + c0 + c4);
        tile[r][c4 + 0] = v.x; tile[r][c4 + 1] = v.y;
        tile[r][c4 + 2] = v.z; tile[r][c4 + 3] = v.w;
        __syncthreads();
        int oc = tid >> 3;
        int orr = (tid & 7) << 2;
        ushort4 o;
        o.x = f2bf(tile[orr + 0][oc]); o.y = f2bf(tile[orr + 1][oc]);
        o.z = f2bf(tile[orr + 2][oc]); o.w = f2bf(tile[orr + 3][oc]);
        *(ushort4*)(in_wT + (size_t)(c0 + oc) * 1024 + r0 + orr) = o;
    } else if (bid < 20480) {
        int m = bid - 16384;
        int tok = tokens[m];
        float4 x = ((const float4*)(embed_w + (size_t)tok * HID))[tid];
        float ss = x.x * x.x + x.y * x.y + x.z * x.z + x.w * x.w;
        for (int off = 32; off > 0; off >>= 1) ss += __shfl_down(ss, off);
        if ((tid & 63) == 0) sh[tid >> 6] = ss;
        __syncthreads();
        float tot = sh[0] + sh[1] + sh[2] + sh[3];
        float scale = rsqrtf(tot / (float)HID + 1e-6f);
        float4 w4 = ((const float4*)norm_w)[tid];
        ushort4 o;
        o.x = f2bf(x.x * scale * w4.x); o.y = f2bf(x.y * scale * w4.y);
        o.z = f2bf(x.z * scale * w4.z); o.w = f2bf(x.w * scale * w4.w);
        *(ushort4*)(xn + (size_t)m * HID + (tid << 2)) = o;
    } else if (bid < 21504) {
        float (*red)[4][64] = (float (*)[4][64])sh;
        int jc = tid >> 6, n = tid & 63;
        bool act = n < VOCAB;
        int k0 = (bid - 20480) * 4;
        float a[4] = {0.f, 0.f, 0.f, 0.f};
        int j0 = jc * 256;
        const float* w0 = out_w + (size_t)(k0 + 0) * HID;
        const float* w1 = out_w + (size_t)(k0 + 1) * HID;
        const float* w2 = out_w + (size_t)(k0 + 2) * HID;
        const float* w3 = out_w + (size_t)(k0 + 3) * HID;
        #pragma unroll 4
        for (int j = j0; j < j0 + 256; j++) {
            float h = act ? head_w[(size_t)j * VOCAB + n] : 0.f;
            a[0] = fmaf(w0[j], h, a[0]);
            a[1] = fmaf(w1[j], h, a[1]);
            a[2] = fmaf(w2[j], h, a[2]);
            a[3] = fmaf(w3[j], h, a[3]);
        }
        #pragma unroll
        for (int i = 0; i < 4; i++) red[jc][i][n] = a[i];
        __syncthreads();
        if (jc == 0) {
            #pragma unroll
            for (int i = 0; i < 4; i++) {
                float s = red[0][i][n] + red[1][i][n] + red[2][i][n] + red[3][i][n];
                W2T[(size_t)n * STT + k0 + i] = f2bf(s);
            }
        }
    } else {
        float (*red)[4][64] = (float (*)[4][64])sh;
        int jc = tid >> 6, n = tid & 63;
        bool act = n < VOCAB;
        int t = bid - 21504;
        const float* src = (t < VOCAB) ? (embed_w + (size_t)t * HID) : out_b;
        float acc = 0.f;
        if (act) {
            int j0 = jc * 256;
            #pragma unroll 4
            for (int j = j0; j < j0 + 256; j++)
                acc = fmaf(src[j], head_w[(size_t)j * VOCAB + n], acc);
        }
        red[jc][0][n] = acc;
        __syncthreads();
        if (tid < 64) {
            float s = red[0][0][n] + red[1][0][n] + red[2][0][n] + red[3][0][n];
            if (t == VOCAB && act) s += head_b[n];
            E_head[t * 64 + n] = s;
        }
    }
}

// ---------------- MFMA GEMM 1 + fused gates + fused chunk-scan (frozen) ------
__global__ __launch_bounds__(512, 2) void gemm_in_mfma(
    const unsigned short* __restrict__ A, const unsigned short* __restrict__ B,
    const float* __restrict__ bias,
    unsigned short* __restrict__ a_out, unsigned short* __restrict__ bx_out,
    unsigned short* __restrict__ c_out,
    float* __restrict__ chunkA, float* __restrict__ chunkH)
{
    extern __shared__ unsigned short lds[];   // 2 bufs * 32768 shorts = 128 KiB
    int tid = threadIdx.x;
    int wid = tid >> 6, lane = tid & 63;
    int wg = blockIdx.x;
    int xcd = wg & 7, loc = wg >> 3;
    int by = ((xcd >> 1) << 2) + (loc & 3);
    int bx = ((xcd & 1) << 5) + (loc >> 2);
    int m0 = by * 256, s0 = bx * 64;
    int wm = wid >> 2, wn = wid & 3;
    int lr = lane & 15, lk = lane >> 4;

    int cb0 = wid * 64, cb1 = 512 + wid * 64;
    int p0 = cb0 + lane, p1 = cb1 + lane;
    int row0 = p0 >> 2, ks0 = (p0 & 3) ^ ((row0 >> 1) & 3);
    int row1 = p1 >> 2, ks1 = (p1 & 3) ^ ((row1 >> 1) & 3);
    int arow0 = m0 + row0, arow1 = m0 + row1;
    int brow0 = ((row0 >> 6) << 12) + s0 + (row0 & 63);
    int brow1 = ((row1 >> 6) << 12) + s0 + (row1 & 63);

#define SHALF(grow0, grow1, b, which, kt, kk) do {                               \
    unsigned short* _d = lds + (b) * 32768 + (which) * 16384 + (kk) * 8192;      \
    __builtin_amdgcn_global_load_lds(                                            \
        (gptr_t)(const void*)(((which) ? B : A) + (size_t)(grow0) * 1024 +       \
                              (kt) * 64 + (kk) * 32 + ks0 * 8),                  \
        (lptr_t)(void*)(_d + (size_t)cb0 * 8), 16, 0, 0);                        \
    __builtin_amdgcn_global_load_lds(                                            \
        (gptr_t)(const void*)(((which) ? B : A) + (size_t)(grow1) * 1024 +       \
                              (kt) * 64 + (kk) * 32 + ks1 * 8),                  \
        (lptr_t)(void*)(_d + (size_t)cb1 * 8), 16, 0, 0);                        \
} while (0)

    int ksw = lk ^ ((lr >> 1) & 3);

#define RD_A(b, kk, mf) \
    (*(const short8v*)&lds[(b) * 32768 + (kk) * 8192 + \
        (((wm * 128 + (mf) * 16 + lr) << 2) + ksw) * 8])
#define RD_B(b, kk, nf) \
    (*(const short8v*)&lds[(b) * 32768 + 16384 + (kk) * 8192 + \
        ((((nf) * 64 + wn * 16 + lr) << 2) + ksw) * 8])

#define MFMA8x2(AF, B0, B1, n0i, n1i) do {                                       \
    __builtin_amdgcn_s_setprio(1);                                               \
    _Pragma("unroll")                                                            \
    for (int mf = 0; mf < 8; mf++) {                                             \
        acc[mf][n0i] = __builtin_amdgcn_mfma_f32_16x16x32_bf16(                  \
            (AF)[mf], (B0), acc[mf][n0i], 0, 0, 0);                              \
        acc[mf][n1i] = __builtin_amdgcn_mfma_f32_16x16x32_bf16(                  \
            (AF)[mf], (B1), acc[mf][n1i], 0, 0, 0);                              \
    }                                                                            \
    __builtin_amdgcn_s_setprio(0);                                               \
} while (0)

#define BAR_IN()  do { __builtin_amdgcn_s_barrier();                              \
    asm volatile("s_waitcnt lgkmcnt(0)" ::: "memory");                           \
    __builtin_amdgcn_sched_barrier(0); } while (0)
#define BAR_OUT() do { asm volatile("" ::: "memory");                             \
    __builtin_amdgcn_s_barrier(); } while (0)

    float4v acc[8][4];
    float4v z = {0.f, 0.f, 0.f, 0.f};
    #pragma unroll
    for (int i = 0; i < 8; i++)
        #pragma unroll
        for (int j = 0; j < 4; j++) acc[i][j] = z;

    SHALF(arow0, arow1, 0, 0, 0, 0); SHALF(brow0, brow1, 0, 1, 0, 0);
    SHALF(arow0, arow1, 0, 0, 0, 1); SHALF(brow0, brow1, 0, 1, 0, 1);
    asm volatile("s_waitcnt vmcnt(0)" ::: "memory");
    __builtin_amdgcn_s_barrier();

    short8v af[8], bf0, bf1;

    for (int kt = 0; kt < 16; ++kt) {
        int cur = kt & 1, nxt = cur ^ 1;
        int ktn = kt < 15 ? kt + 1 : 15;
        #pragma unroll
        for (int mf = 0; mf < 8; mf++) af[mf] = RD_A(cur, 0, mf);
        bf0 = RD_B(cur, 0, 0); bf1 = RD_B(cur, 0, 1);
        asm volatile("s_waitcnt vmcnt(4)" ::: "memory");
        SHALF(arow0, arow1, nxt, 0, ktn, 0);
        BAR_IN();
        MFMA8x2(af, bf0, bf1, 0, 1);
        BAR_OUT();
        bf0 = RD_B(cur, 0, 2); bf1 = RD_B(cur, 0, 3);
        SHALF(brow0, brow1, nxt, 1, ktn, 0);
        BAR_IN();
        MFMA8x2(af, bf0, bf1, 2, 3);
        BAR_OUT();
        #pragma unroll
        for (int mf = 0; mf < 8; mf++) af[mf] = RD_A(cur, 1, mf);
        bf0 = RD_B(cur, 1, 0); bf1 = RD_B(cur, 1, 1);
        asm volatile("s_waitcnt vmcnt(4)" ::: "memory");
        SHALF(arow0, arow1, nxt, 0, ktn, 1);
        BAR_IN();
        MFMA8x2(af, bf0, bf1, 0, 1);
        BAR_OUT();
        bf0 = RD_B(cur, 1, 2); bf1 = RD_B(cur, 1, 3);
        SHALF(brow0, brow1, nxt, 1, ktn, 1);
        BAR_IN();
        MFMA8x2(af, bf0, bf1, 2, 3);
        BAR_OUT();
    }

    int s = s0 + wn * 16 + lr;
    float b_xg = bias[s];
    float b_a  = bias[4096 + s];
    float b_b  = bias[8192 + s];
    float b_c  = bias[12288 + s];
    int rbase = lk << 2;
    int bb = m0 >> 11;
    int t0 = m0 & 2047;
    int ch = bb * STT + s;

    #pragma unroll
    for (int cc = 0; cc < 4; cc++) {
        float Afr[2], Hfr[2];
        #pragma unroll
        for (int e = 0; e < 2; e++) {
            int mf = cc * 2 + e;
            float Al = 1.f, Hl = 0.f;
            #pragma unroll
            for (int q = 0; q < 4; q++) {
                int m = m0 + wm * 128 + mf * 16 + rbase + q;
                size_t idx = (size_t)m * STT + s;
                float xg = acc[mf][0][q] + b_xg;
                float av = sigmoidf_(acc[mf][1][q] + b_a);
                float bxv = sigmoidf_(acc[mf][2][q] + b_b) * xg;
                float cv = sigmoidf_(acc[mf][3][q] + b_c);
                unsigned short au = f2bf(av), bu = f2bf(bxv);
                a_out[idx]  = au;
                bx_out[idx] = bu;
                c_out[idx]  = f2bf(cv);
                float ar = bf2f(au), br = bf2f(bu);
                Hl = fmaf(ar, Hl, br);
                Al = ar * Al;
            }
            #pragma unroll
            for (int d = 1; d <= 2; d <<= 1) {
                float Ap = __shfl(Al, lane - (d << 4));
                float Hp = __shfl(Hl, lane - (d << 4));
                if (lk >= d) { Hl = fmaf(Al, Hp, Hl); Al = Al * Ap; }
            }
            Afr[e] = Al; Hfr[e] = Hl;
        }
        if (lk == 3) {
            float Ac = Afr[1] * Afr[0];
            float Hc = fmaf(Afr[1], Hfr[0], Hfr[1]);
            int qg = (t0 >> 5) + wm * 4 + cc;
            chunkA[ch * NCHUNK + qg] = Ac;
            chunkH[ch * NCHUNK + qg] = Hc;
        }
    }
#undef SHALF
#undef RD_A
#undef RD_B
#undef MFMA8x2
#undef BAR_IN
#undef BAR_OUT
}

__global__ __launch_bounds__(256) void scan_phase2(
    const float* __restrict__ chunkA, const float* __restrict__ chunkH,
    float* __restrict__ carry)
{
    int ch = blockIdx.x * 256 + threadIdx.x;
    float c = 0.f;
    for (int q = 0; q < NCHUNK; q++) {
        carry[ch * NCHUNK + q] = c;
        c = fmaf(chunkA[ch * NCHUNK + q], c, chunkH[ch * NCHUNK + q]);
    }
}

// ---------------- fused scan3 + logits GEMM ----------------
// grid 256: mt = wg&31 (128-token tile = 4 chunks), sl = wg>>5 (512-ch slice).
// Per 128-ch subtile ks (4): wave w scans chunk w (carry-init per chunk, 2 ch/
// thread, uint loads), writes bf16 y into LDS tile [128][128] with XOR-chunk
// swizzle; stages W2T slice via gload_lds with inverse-swizzled source; then
// 32 MFMA accumulate. y never touches HBM.
__global__ __launch_bounds__(256) void scan_logits(
    const unsigned short* __restrict__ a_buf, const unsigned short* __restrict__ bx_buf,
    const unsigned short* __restrict__ c_buf, const float* __restrict__ carry,
    const unsigned short* __restrict__ W2T, float* __restrict__ part)
{
    __shared__ __align__(16) unsigned short y_lds[128 * 128];   // 32 KiB
    __shared__ __align__(16) unsigned short b_lds[64 * 128];    // 16 KiB
    int tid = threadIdx.x;
    int wg = blockIdx.x;
    int mt = wg & 31, sl = wg >> 5;
    int m0 = mt * 128;
    int bb = m0 >> 11;
    int q0 = (m0 & 2047) >> 5;
    int lane = tid & 63, wid = tid >> 6;
    int lr = lane & 15, lk = lane >> 4;

    float4v acc[2][4];
    float4v z = {0.f, 0.f, 0.f, 0.f};
    #pragma unroll
    for (int e = 0; e < 2; e++)
        #pragma unroll
        for (int nf = 0; nf < 4; nf++) acc[e][nf] = z;

    for (int ks = 0; ks < 4; ++ks) {
        int sbase = sl * 512 + ks * 128;
        #pragma unroll
        for (int i = 0; i < 4; i++) {
            int cb = i * 256 + wid * 64;
            int p = cb + lane;
            int row = p >> 4, csw = p & 15;
            int c = csw ^ (row & 7);
            __builtin_amdgcn_global_load_lds(
                (gptr_t)(const void*)(W2T + (size_t)row * STT + sbase + c * 8),
                (lptr_t)(void*)(b_lds + (size_t)cb * 8), 16, 0, 0);
        }
        {
            int chq = wid;
            int s = sbase + lane * 2;
            int q = q0 + chq;
            size_t cidx = ((size_t)(bb * STT + s)) * NCHUNK + q;
            float h0 = carry[cidx];
            float h1 = carry[cidx + NCHUNK];
            size_t gb = (size_t)(m0 + chq * 32) * STT + s;
            const unsigned int* ap = (const unsigned int*)(a_buf + gb);
            const unsigned int* bp = (const unsigned int*)(bx_buf + gb);
            const unsigned int* cp = (const unsigned int*)(c_buf + gb);
            const int stride = STT / 2;
            #pragma unroll 4
            for (int i = 0; i < 32; i++) {
                unsigned int au = ap[(size_t)i * stride];
                unsigned int bu = bp[(size_t)i * stride];
                unsigned int cu = cp[(size_t)i * stride];
                float a0 = bf2f((unsigned short)(au & 0xffff));
                float a1 = bf2f((unsigned short)(au >> 16));
                float b0 = bf2f((unsigned short)(bu & 0xffff));
                float b1 = bf2f((unsigned short)(bu >> 16));
                float c0 = bf2f((unsigned short)(cu & 0xffff));
                float c1 = bf2f((unsigned short)(cu >> 16));
                h0 = fmaf(a0, h0, b0);
                h1 = fmaf(a1, h1, b1);
                unsigned int yp = (unsigned int)f2bf(c0 * h0) |
                                  ((unsigned int)f2bf(c1 * h1) << 16);
                int row = chq * 32 + i;
                int cw = (lane >> 2) ^ (row & 7);
                *(unsigned int*)&y_lds[row * 128 + (cw << 3) + (lane & 3) * 2] = yp;
            }
        }
        __syncthreads();
        #pragma unroll
        for (int kt2 = 0; kt2 < 4; kt2++) {
            short8v af[2], bf[4];
            #pragma unroll
            for (int e = 0; e < 2; e++) {
                int row = (wid * 2 + e) * 16 + lr;
                int c = kt2 * 4 + lk;
                af[e] = *(const short8v*)&y_lds[row * 128 + ((c ^ (row & 7)) << 3)];
            }
            #pragma unroll
            for (int nf = 0; nf < 4; nf++) {
                int row = nf * 16 + lr;
                int c = kt2 * 4 + lk;
                bf[nf] = *(const short8v*)&b_lds[row * 128 + ((c ^ (row & 7)) << 3)];
            }
            __builtin_amdgcn_s_setprio(1);
            #pragma unroll
            for (int e = 0; e < 2; e++)
                #pragma unroll
                for (int nf = 0; nf < 4; nf++)
                    acc[e][nf] = __builtin_amdgcn_mfma_f32_16x16x32_bf16(
                        af[e], bf[nf], acc[e][nf], 0, 0, 0);
            __builtin_amdgcn_s_setprio(0);
        }
        __syncthreads();
    }

    float* pb = part + (size_t)sl * MTOK * 64;
    int rbase = lk << 2;
    #pragma unroll
    for (int e = 0; e < 2; e++)
        #pragma unroll
        for (int nf = 0; nf < 4; nf++) {
            int n = nf * 16 + lr;
            #pragma unroll
            for (int q = 0; q < 4; q++) {
                int m = m0 + (wid * 2 + e) * 16 + rbase + q;
                pb[(size_t)m * 64 + n] = acc[e][nf][q];
            }
        }
}

// ---------------- logits reduce: sum 8 partials + E_head[tok] + bias2 -------
__global__ __launch_bounds__(64) void logits_reduce(
    const float* __restrict__ part, const float* __restrict__ E_head,
    const int* __restrict__ tokens, float* __restrict__ logits)
{
    int m = blockIdx.x;
    int n = threadIdx.x;
    if (n >= VOCAB) return;
    int tok = tokens[m];
    float s = E_head[tok * 64 + n] + E_head[VOCAB * 64 + n];
    #pragma unroll
    for (int sl = 0; sl < 8; sl++)
        s += part[(size_t)sl * MTOK * 64 + (size_t)m * 64 + n];
    logits[(size_t)m * VOCAB + n] = s;
}

extern "C" void kernel_launch(void* const* d_in, const int* in_sizes, int n_in,
                              void* d_out, int out_size, void* d_ws, size_t ws_size,
                              hipStream_t stream) {
    const int*   tokens  = (const int*)d_in[0];
    const float* embed_w = (const float*)d_in[1];
    const float* norm_w  = (const float*)d_in[2];
    const float* in_w    = (const float*)d_in[3];
    const float* in_b    = (const float*)d_in[4];
    const float* out_w   = (const float*)d_in[5];
    const float* out_b   = (const float*)d_in[6];
    const float* head_w  = (const float*)d_in[7];
    const float* head_b  = (const float*)d_in[8];
    float* logits = (float*)d_out;

    char* w = (char*)d_ws;
    unsigned short* a_buf  = (unsigned short*)w;                    // 32 MiB
    unsigned short* bx_buf = (unsigned short*)(w + 33554432);       // 32 MiB
    unsigned short* c_buf  = (unsigned short*)(w + 67108864);       // 32 MiB
    unsigned short* W2T    = (unsigned short*)(w + 100663296);      // 512 KiB
    float*          E_head = (float*)(w + 101711872);               // 16 KiB
    float*          part   = (float*)(w + 102760448);               // 8 MiB
    unsigned short* in_wT  = (unsigned short*)(w + 167772160);      // 32 MiB
    unsigned short* xn     = (unsigned short*)(w + 201326592);      // 8 MiB
    float* chunkA = (float*)(w + 209715200);
    float* chunkH = chunkA + 8192 * NCHUNK;
    float* carry  = chunkH + 8192 * NCHUNK;

    hipLaunchKernelGGL(fused_pre, dim3(16384 + 4096 + 1024 + VOCAB + 1), dim3(256), 0, stream,
                       tokens, embed_w, norm_w, in_w, out_w, head_w, out_b, head_b,
                       in_wT, xn, W2T, E_head);
    hipLaunchKernelGGL(gemm_in_mfma, dim3(1024), dim3(512), 131072, stream,
                       xn, in_wT, in_b, a_buf, bx_buf, c_buf, chunkA, chunkH);
    hipLaunchKernelGGL(scan_phase2, dim3(32), dim3(256), 0, stream,
                       chunkA, chunkH, carry);
    hipLaunchKernelGGL(scan_logits, dim3(256), dim3(256), 0, stream,
                       a_buf, bx_buf, c_buf, carry, W2T, part);
    hipLaunchKernelGGL(logits_reduce, dim3(MTOK), dim3(64), 0, stream,
                       part, E_head, tokens, logits);
}